// Round 1
// baseline (188.373 us; speedup 1.0000x reference)
//
#include <hip/hip_runtime.h>
#include <cstdint>

// Attention: B=4, S=4096, WORD=512, ED=64, fp32 in/out.
// Strategy: bf16 MFMA (16x16x32) everywhere; fp32 softmax; errors damped by
// diffuse softmax (sqrt(sum p^2) ~ 0.03) -> predicted absmax ~1e-3 vs 5.5e-3.

typedef __bf16 bf16x8 __attribute__((ext_vector_type(8)));
typedef float f32x4 __attribute__((ext_vector_type(4)));

#define SCALEQ 0.18033688011112042f  // log2(e)/sqrt(64)

// ws layout (bytes)
#define WT_OFF 0u               // bf16 Wt[3][64][512]   = 196608 B
#define Q_OFF  262144u          // bf16 Q [16384][64]    = 2 MB (pre-scaled)
#define K_OFF  2359296u         // bf16 K [16384][64]    = 2 MB
#define VT_OFF 4456448u         // bf16 Vt[4][64][4096]  = 2 MB
// total ws need = 6553600 B

__device__ __forceinline__ unsigned pk_bf16(float a, float b) {
  unsigned ua = __builtin_bit_cast(unsigned, a);
  unsigned ub = __builtin_bit_cast(unsigned, b);
  ua += 0x7FFFu + ((ua >> 16) & 1u);
  ub += 0x7FFFu + ((ub >> 16) & 1u);
  return (ua >> 16) | (ub & 0xFFFF0000u);
}
__device__ __forceinline__ unsigned short bf16_1(float a) {
  unsigned ua = __builtin_bit_cast(unsigned, a);
  ua += 0x7FFFu + ((ua >> 16) & 1u);
  return (unsigned short)(ua >> 16);
}

// ---------------- kernel 0: W fp32 [512][64] -> Wt bf16 [mat][64][512] ----
__global__ __launch_bounds__(256) void prep_w(const float* __restrict__ wq,
                                              const float* __restrict__ wk,
                                              const float* __restrict__ wv,
                                              unsigned short* __restrict__ wt) {
  unsigned tid = blockIdx.x * 256u + threadIdx.x;   // 98304 total
  unsigned mat = tid >> 15;
  unsigned rem = tid & 32767u;
  const float* w = (mat == 0) ? wq : (mat == 1) ? wk : wv;
  float v = w[rem];                                  // coalesced
  unsigned k = rem >> 6, n = rem & 63u;
  wt[mat * 32768u + n * 512u + k] = bf16_1(v);       // scattered b16 (small)
}

// ---------------- kernel 1: QKV projection (MFMA) --------------------------
// grid 256, block 256 (4 waves x 16 rows). K-chunks of 64.
__global__ __launch_bounds__(256) void qkv_proj(
    const float* __restrict__ x, const unsigned short* __restrict__ wt,
    const float* __restrict__ bq, const float* __restrict__ bk,
    const float* __restrict__ bv, unsigned short* __restrict__ qo,
    unsigned short* __restrict__ ko, unsigned short* __restrict__ vto) {
  __shared__ __align__(16) char sm[32768];  // xs 8KB | wt 3x8KB
  const unsigned t = threadIdx.x;
  const unsigned row0 = blockIdx.x * 64u;
  const unsigned w = t >> 6, lane = t & 63u, l15 = lane & 15u, quad = lane >> 4;

  f32x4 zero = {0.f, 0.f, 0.f, 0.f};
  f32x4 acc[3][4];
#pragma unroll
  for (int m = 0; m < 3; m++)
#pragma unroll
    for (int n = 0; n < 4; n++) acc[m][n] = zero;

  for (unsigned kc = 0; kc < 8u; kc++) {
    __syncthreads();
    {  // stage x tile 64x64 -> bf16, granule-swizzled
      unsigned r = t >> 2, c0 = (t & 3u) * 16u;
      const float* src = x + (row0 + r) * 512u + kc * 64u + c0;
      float4 f0 = ((const float4*)src)[0];
      float4 f1 = ((const float4*)src)[1];
      float4 f2 = ((const float4*)src)[2];
      float4 f3 = ((const float4*)src)[3];
      float ff[16] = {f0.x, f0.y, f0.z, f0.w, f1.x, f1.y, f1.z, f1.w,
                      f2.x, f2.y, f2.z, f2.w, f3.x, f3.y, f3.z, f3.w};
      unsigned p[8];
#pragma unroll
      for (int i = 0; i < 8; i++) p[i] = pk_bf16(ff[2 * i], ff[2 * i + 1]);
      unsigned g0 = 2u * (t & 3u);
      int4 v0 = make_int4(p[0], p[1], p[2], p[3]);
      int4 v1 = make_int4(p[4], p[5], p[6], p[7]);
      *(int4*)(sm + r * 128u + (((g0) ^ (r & 7u)) << 4)) = v0;
      *(int4*)(sm + r * 128u + (((g0 + 1u) ^ (r & 7u)) << 4)) = v1;
    }
#pragma unroll
    for (int m = 0; m < 3; m++) {  // stage Wt tiles (already bf16): copy
#pragma unroll
      for (int i = 0; i < 2; i++) {
        unsigned u = t + 256u * (unsigned)i;
        unsigned n = u >> 3, g = u & 7u;
        int4 v = *(const int4*)(wt + (unsigned)m * 32768u + n * 512u +
                                kc * 64u + g * 8u);
        *(int4*)(sm + 8192u + (unsigned)m * 8192u + n * 128u +
                 ((g ^ (n & 7u)) << 4)) = v;
      }
    }
    __syncthreads();
    bf16x8 a[2];
    unsigned arow = w * 16u + l15;
#pragma unroll
    for (int h = 0; h < 2; h++) {
      int4 av = *(const int4*)(sm + arow * 128u +
                               ((((unsigned)h * 4u + quad) ^ (arow & 7u)) << 4));
      a[h] = __builtin_bit_cast(bf16x8, av);
    }
#pragma unroll
    for (int m = 0; m < 3; m++)
#pragma unroll
      for (int ns = 0; ns < 4; ns++) {
        unsigned n = (unsigned)ns * 16u + l15;
#pragma unroll
        for (int h = 0; h < 2; h++) {
          int4 b4 = *(const int4*)(sm + 8192u + (unsigned)m * 8192u + n * 128u +
                                   ((((unsigned)h * 4u + quad) ^ (n & 7u)) << 4));
          acc[m][ns] = __builtin_amdgcn_mfma_f32_16x16x32_bf16(
              a[h], __builtin_bit_cast(bf16x8, b4), acc[m][ns], 0, 0, 0);
        }
      }
  }
  // epilogue: Q scaled+bf16 row-major, K bf16 row-major, V bf16 transposed
#pragma unroll
  for (int ns = 0; ns < 4; ns++) {
    unsigned n = (unsigned)ns * 16u + l15;
    float bqv = bq[n], bkv = bk[n], bvv = bv[n];
#pragma unroll
    for (int r = 0; r < 4; r++) {
      unsigned rg = row0 + w * 16u + quad * 4u + (unsigned)r;
      qo[rg * 64u + n] = bf16_1((acc[0][ns][r] + bqv) * SCALEQ);
      ko[rg * 64u + n] = bf16_1(acc[1][ns][r] + bkv);
      unsigned bb = rg >> 12, s = rg & 4095u;
      vto[bb * 262144u + n * 4096u + s] = bf16_1(acc[2][ns][r] + bvv);
    }
  }
}

// ---------------- kernel 2: flash attention (S^T / O^T form) ---------------
// grid 256 = b(4) x qtile(64); block 256 = 4 waves x 16 q-rows.
__global__ __launch_bounds__(256) void attn(const unsigned short* __restrict__ qws,
                                            const unsigned short* __restrict__ kws,
                                            const unsigned short* __restrict__ vtws,
                                            float* __restrict__ out) {
  __shared__ __align__(16) char sm[24576];  // K 8KB | Vt 8KB | P 4x2KB
  const unsigned t = threadIdx.x;
  const unsigned w = t >> 6, lane = t & 63u, l15 = lane & 15u, quad = lane >> 4;
  const unsigned b = blockIdx.x >> 6, qt = blockIdx.x & 63u;
  const unsigned q0 = qt * 64u;
  const unsigned Pb = 16384u + w * 2048u;

  bf16x8 qf[2];  // Q fragments live in registers for the whole K loop
#pragma unroll
  for (int h = 0; h < 2; h++) {
    const int4* src = (const int4*)(qws + ((b * 4096u + q0 + w * 16u + l15) * 64u +
                                           ((unsigned)h * 4u + quad) * 8u));
    qf[h] = __builtin_bit_cast(bf16x8, *src);
  }
  f32x4 zero = {0.f, 0.f, 0.f, 0.f};
  f32x4 accO[4];
#pragma unroll
  for (int i = 0; i < 4; i++) accO[i] = zero;
  float mh = -1e30f, lsum = 0.f;

  for (unsigned kt = 0; kt < 64u; kt++) {
    __syncthreads();
#pragma unroll
    for (int i = 0; i < 2; i++) {  // stage K-tile + Vt-tile (swizzled)
      unsigned u = t + 256u * (unsigned)i;
      unsigned row = u >> 3, g = u & 7u;
      int4 kv = *(const int4*)(kws + ((b * 4096u + kt * 64u + row) * 64u + g * 8u));
      *(int4*)(sm + row * 128u + ((g ^ (row & 7u)) << 4)) = kv;
      int4 vv = *(const int4*)(vtws + (b * 262144u + row * 4096u + kt * 64u + g * 8u));
      *(int4*)(sm + 8192u + row * 128u + ((g ^ (row & 7u)) << 4)) = vv;
    }
    __syncthreads();
    // S^T = K * Q^T   (C: col=q=lane&15, row=key=quad*4+reg)
    f32x4 s[4];
#pragma unroll
    for (int ks = 0; ks < 4; ks++) {
      unsigned key = (unsigned)ks * 16u + l15;
      int4 k0 = *(const int4*)(sm + key * 128u + (((0u + quad) ^ (key & 7u)) << 4));
      int4 k1 = *(const int4*)(sm + key * 128u + (((4u + quad) ^ (key & 7u)) << 4));
      f32x4 z = zero;
      z = __builtin_amdgcn_mfma_f32_16x16x32_bf16(__builtin_bit_cast(bf16x8, k0),
                                                  qf[0], z, 0, 0, 0);
      z = __builtin_amdgcn_mfma_f32_16x16x32_bf16(__builtin_bit_cast(bf16x8, k1),
                                                  qf[1], z, 0, 0, 0);
      s[ks] = z;
    }
    // online softmax (per-lane q; reduce across quads only)
    float vm = s[0][0];
#pragma unroll
    for (int ks = 0; ks < 4; ks++)
#pragma unroll
      for (int r = 0; r < 4; r++) vm = fmaxf(vm, s[ks][r]);
    vm = fmaxf(vm, __shfl_xor(vm, 16));
    vm = fmaxf(vm, __shfl_xor(vm, 32));
    float mnew = fmaxf(mh, vm);
    float alpha = exp2f(mh - mnew);
    mh = mnew;
    float ps = 0.f;
#pragma unroll
    for (int ks = 0; ks < 4; ks++)
#pragma unroll
      for (int r = 0; r < 4; r++) {
        float p = exp2f(s[ks][r] - mnew);
        s[ks][r] = p;
        ps += p;
      }
    lsum = lsum * alpha + ps;
#pragma unroll
    for (int i = 0; i < 4; i++) accO[i] = accO[i] * alpha;
    // write P (bf16) to per-wave LDS region; no barrier (wave-private)
#pragma unroll
    for (int ks = 0; ks < 4; ks++) {
      unsigned gw = ((unsigned)ks * 2u + (quad >> 1)) ^ (l15 & 7u);
#pragma unroll
      for (int c = 0; c < 2; c++) {
        unsigned pk = pk_bf16(s[ks][2 * c], s[ks][2 * c + 1]);
        *(unsigned*)(sm + Pb + l15 * 128u + (gw << 4) + ((quad & 1u) << 3) +
                     ((unsigned)c << 2)) = pk;
      }
    }
    bf16x8 pf[2];
#pragma unroll
    for (int h = 0; h < 2; h++) {
      int4 pv = *(const int4*)(sm + Pb + l15 * 128u +
                               ((((unsigned)h * 4u + quad) ^ (l15 & 7u)) << 4));
      pf[h] = __builtin_bit_cast(bf16x8, pv);
    }
    // O^T += V^T * P^T
#pragma unroll
    for (int ds = 0; ds < 4; ds++) {
      unsigned dout = (unsigned)ds * 16u + l15;
#pragma unroll
      for (int h = 0; h < 2; h++) {
        int4 vv = *(const int4*)(sm + 8192u + dout * 128u +
                                 ((((unsigned)h * 4u + quad) ^ (dout & 7u)) << 4));
        accO[ds] = __builtin_amdgcn_mfma_f32_16x16x32_bf16(
            __builtin_bit_cast(bf16x8, vv), pf[h], accO[ds], 0, 0, 0);
      }
    }
  }
  float lt = lsum;
  lt += __shfl_xor(lt, 16);
  lt += __shfl_xor(lt, 32);
  float inv = 1.0f / lt;
  __syncthreads();  // all waves done with K/Vt/P before Zbuf overlay
  unsigned Zb = w * 4352u;  // 16 rows x 68 floats per wave
#pragma unroll
  for (int ds = 0; ds < 4; ds++)
#pragma unroll
    for (int r = 0; r < 4; r++) {
      unsigned dout = (unsigned)ds * 16u + quad * 4u + (unsigned)r;
      *(float*)(sm + Zb + l15 * 272u + dout * 4u) = accO[ds][r] * inv;
    }
#pragma unroll
  for (int i = 0; i < 4; i++) {  // coalesced float4 stores
    unsigned q2 = (lane >> 4) + (unsigned)i * 4u;
    unsigned d0 = (lane & 15u) * 4u;
    int4 v = *(const int4*)(sm + Zb + q2 * 272u + d0 * 4u);
    *(int4*)(out + ((b * 4096u + q0 + w * 16u + q2) * 64u + d0)) = v;
  }
}

extern "C" void kernel_launch(void* const* d_in, const int* in_sizes, int n_in,
                              void* d_out, int out_size, void* d_ws,
                              size_t ws_size, hipStream_t stream) {
  const float* x = (const float*)d_in[0];
  const float* Wq = (const float*)d_in[1];
  const float* bq = (const float*)d_in[2];
  const float* Wk = (const float*)d_in[3];
  const float* bk = (const float*)d_in[4];
  const float* Wv = (const float*)d_in[5];
  const float* bv = (const float*)d_in[6];
  char* ws = (char*)d_ws;
  unsigned short* wt = (unsigned short*)(ws + WT_OFF);
  unsigned short* qb = (unsigned short*)(ws + Q_OFF);
  unsigned short* kb = (unsigned short*)(ws + K_OFF);
  unsigned short* vtb = (unsigned short*)(ws + VT_OFF);
  float* outp = (float*)d_out;

  prep_w<<<384, 256, 0, stream>>>(Wq, Wk, Wv, wt);
  qkv_proj<<<256, 256, 0, stream>>>(x, wt, bq, bk, bv, qb, kb, vtb);
  attn<<<256, 256, 0, stream>>>(qb, kb, vtb, outp);
}

// Round 2
// 140.319 us; speedup vs baseline: 1.3425x; 1.3425x over previous
//
#include <hip/hip_runtime.h>
#include <cstdint>

// Attention: B=4, S=4096, WORD=512, ED=64, fp32 in/out.
// R2: fix 1-block/CU latency-bound regime (R1: MfmaUtil 6.9%, Occ 11%).
//  - attn: 128q blocks, 32x32x16 MFMA, 4-way K-split (grid 512) + combine.
//  - qkv: 32-row blocks (grid 512), waves split over (row-half x n-half).

typedef __bf16 bf16x8 __attribute__((ext_vector_type(8)));
typedef float f32x4 __attribute__((ext_vector_type(4)));
typedef float f32x16 __attribute__((ext_vector_type(16)));

#define SCALEQ 0.18033688011112042f  // log2(e)/sqrt(64)

// ws layout (bytes)
#define WT_OFF 0u          // bf16 Wt[3][64][512]        = 192 KB
#define Q_OFF  262144u     // bf16 Q [16384][64] (scaled)= 2 MB
#define K_OFF  2359296u    // bf16 K [16384][64]         = 2 MB
#define VT_OFF 4456448u    // bf16 Vt[4][64][4096]       = 2 MB
#define ML_OFF 6553600u    // float2 [4][16384]          = 512 KB
#define OP_OFF 7077888u    // f32 [4][16384][64]         = 16 MB (ends 23.9MB)

__device__ __forceinline__ unsigned pk_bf16(float a, float b) {
  unsigned ua = __builtin_bit_cast(unsigned, a);
  unsigned ub = __builtin_bit_cast(unsigned, b);
  ua += 0x7FFFu + ((ua >> 16) & 1u);
  ub += 0x7FFFu + ((ub >> 16) & 1u);
  return (ua >> 16) | (ub & 0xFFFF0000u);
}
__device__ __forceinline__ unsigned short bf16_1(float a) {
  unsigned ua = __builtin_bit_cast(unsigned, a);
  ua += 0x7FFFu + ((ua >> 16) & 1u);
  return (unsigned short)(ua >> 16);
}

// ---------------- kernel 0: W fp32 [512][64] -> Wt bf16 [mat][64][512] ----
__global__ __launch_bounds__(256) void prep_w(const float* __restrict__ wq,
                                              const float* __restrict__ wk,
                                              const float* __restrict__ wv,
                                              unsigned short* __restrict__ wt) {
  unsigned tid = blockIdx.x * 256u + threadIdx.x;  // 98304 total
  unsigned mat = tid >> 15;
  unsigned rem = tid & 32767u;
  const float* w = (mat == 0) ? wq : (mat == 1) ? wk : wv;
  float v = w[rem];
  unsigned k = rem >> 6, n = rem & 63u;
  wt[mat * 32768u + n * 512u + k] = bf16_1(v);
}

// ---------------- kernel 1: QKV projection (MFMA 16x16x32) -----------------
// grid 512 (32 rows/block), block 256 = 4 waves; wave = (row-half, n-half).
__global__ __launch_bounds__(256) void qkv_proj(
    const float* __restrict__ x, const unsigned short* __restrict__ wt,
    const float* __restrict__ bq, const float* __restrict__ bk,
    const float* __restrict__ bv, unsigned short* __restrict__ qo,
    unsigned short* __restrict__ ko, unsigned short* __restrict__ vto) {
  __shared__ __align__(16) char sm[28672];  // x 4KB | Wt 24KB
  const unsigned t = threadIdx.x;
  const unsigned row0 = blockIdx.x * 32u;
  const unsigned w = t >> 6, lane = t & 63u, l15 = lane & 15u, quad = lane >> 4;
  const unsigned rsel = w & 1u;   // which 16-row half
  const unsigned nsel = w >> 1;   // which pair of n-tiles

  f32x4 zero = {0.f, 0.f, 0.f, 0.f};
  f32x4 acc[3][2];
#pragma unroll
  for (int m = 0; m < 3; m++)
#pragma unroll
    for (int j = 0; j < 2; j++) acc[m][j] = zero;

  for (unsigned kc = 0; kc < 8u; kc++) {
    __syncthreads();
    {  // stage x: 32 rows x 64 cols fp32 -> bf16, swizzled
      unsigned r = t >> 3, g = t & 7u;
      const float* src = x + (row0 + r) * 512u + kc * 64u + g * 8u;
      float4 f0 = ((const float4*)src)[0];
      float4 f1 = ((const float4*)src)[1];
      int4 v = make_int4(pk_bf16(f0.x, f0.y), pk_bf16(f0.z, f0.w),
                         pk_bf16(f1.x, f1.y), pk_bf16(f1.z, f1.w));
      *(int4*)(sm + r * 128u + ((g ^ (r & 7u)) << 4)) = v;
    }
#pragma unroll
    for (int i = 0; i < 6; i++) {  // stage Wt: 3 x 64n x 64k bf16
      unsigned u = t + 256u * (unsigned)i;
      unsigned m = u >> 9, n = (u >> 3) & 63u, g = u & 7u;
      int4 v = *(const int4*)(wt + m * 32768u + n * 512u + kc * 64u + g * 8u);
      *(int4*)(sm + 4096u + m * 8192u + n * 128u + ((g ^ (n & 7u)) << 4)) = v;
    }
    __syncthreads();
    unsigned arow = rsel * 16u + l15;
    bf16x8 a[2];
#pragma unroll
    for (int h = 0; h < 2; h++) {
      int4 av = *(const int4*)(sm + arow * 128u +
                               ((((unsigned)h * 4u + quad) ^ (arow & 7u)) << 4));
      a[h] = __builtin_bit_cast(bf16x8, av);
    }
#pragma unroll
    for (int m = 0; m < 3; m++)
#pragma unroll
      for (int j = 0; j < 2; j++) {
        unsigned n = (nsel * 2u + (unsigned)j) * 16u + l15;
#pragma unroll
        for (int h = 0; h < 2; h++) {
          int4 b4 = *(const int4*)(sm + 4096u + (unsigned)m * 8192u + n * 128u +
                                   ((((unsigned)h * 4u + quad) ^ (n & 7u)) << 4));
          acc[m][j] = __builtin_amdgcn_mfma_f32_16x16x32_bf16(
              a[h], __builtin_bit_cast(bf16x8, b4), acc[m][j], 0, 0, 0);
        }
      }
  }
  // epilogue: direct stores (qo/ko 32B-segment coalesced; vto packed dwordx2)
  unsigned sb = row0 + rsel * 16u + quad * 4u;
  unsigned bb = sb >> 12, s = sb & 4095u;
#pragma unroll
  for (int j = 0; j < 2; j++) {
    unsigned n = (nsel * 2u + (unsigned)j) * 16u + l15;
    float bqv = bq[n], bkv = bk[n], bvv = bv[n];
#pragma unroll
    for (int r = 0; r < 4; r++) {
      qo[(sb + (unsigned)r) * 64u + n] = bf16_1((acc[0][j][r] + bqv) * SCALEQ);
      ko[(sb + (unsigned)r) * 64u + n] = bf16_1(acc[1][j][r] + bkv);
    }
    unsigned p0 = pk_bf16(acc[2][j][0] + bvv, acc[2][j][1] + bvv);
    unsigned p1 = pk_bf16(acc[2][j][2] + bvv, acc[2][j][3] + bvv);
    *(int2*)(vto + bb * 262144u + n * 4096u + s) = make_int2(p0, p1);
  }
}

// ---------------- kernel 2: flash attention, K-split, 32x32x16 -------------
// grid 512 = ks(4) x b(4) x qt(32); block 256 = 4 waves x 32 q each.
// Writes unnormalized O-partials + (m,l) per (ks, q).
__global__ __launch_bounds__(256) void attn(
    const unsigned short* __restrict__ qws, const unsigned short* __restrict__ kws,
    const unsigned short* __restrict__ vtws, float2* __restrict__ ml,
    float* __restrict__ op) {
  __shared__ __align__(16) char sm[32768];  // K 8KB | Vt 8KB | P 4x4KB
  const unsigned t = threadIdx.x;
  const unsigned w = t >> 6, lane = t & 63u, l31 = lane & 31u, hl = lane >> 5;
  const unsigned ks = blockIdx.x >> 7;
  const unsigned b = (blockIdx.x >> 5) & 3u;
  const unsigned qt = blockIdx.x & 31u;
  const unsigned qw = qt * 128u + w * 32u;  // wave's q base (within batch)
  const unsigned k0 = ks * 1024u;
  const unsigned Pb = 16384u + w * 4096u;

  // Q frags (B-operand of 32x32x16: n=q=lane&31, k=d chunk), registers.
  bf16x8 qf[4];
#pragma unroll
  for (int kq = 0; kq < 4; kq++) {
    const int4* src = (const int4*)(qws + ((b * 4096u + qw + l31) * 64u +
                                           (unsigned)kq * 16u + hl * 8u));
    qf[kq] = __builtin_bit_cast(bf16x8, *src);
  }
  f32x16 accO[2];
#pragma unroll
  for (int dh = 0; dh < 2; dh++)
#pragma unroll
    for (int r = 0; r < 16; r++) accO[dh][r] = 0.f;
  float mh = -1e30f, lsum = 0.f;

  for (unsigned kt = 0; kt < 16u; kt++) {
    __syncthreads();
#pragma unroll
    for (int i = 0; i < 2; i++) {  // stage K-tile (64k x 64d) + Vt (64d x 64k)
      unsigned u = t + 256u * (unsigned)i;
      unsigned row = u >> 3, g = u & 7u;
      int4 kv = *(const int4*)(kws + ((b * 4096u + k0 + kt * 64u + row) * 64u + g * 8u));
      *(int4*)(sm + row * 128u + ((g ^ (row & 7u)) << 4)) = kv;
      int4 vv = *(const int4*)(vtws + (b * 262144u + row * 4096u + k0 + kt * 64u + g * 8u));
      *(int4*)(sm + 8192u + row * 128u + ((g ^ (row & 7u)) << 4)) = vv;
    }
    __syncthreads();
    // S^T = K * Q^T : two 32-key C tiles. C: col=q=lane&31,
    // row(key) = (reg&3) + 8*(reg>>2) + 4*hl (+ 32*kh).
    f32x16 st[2];
#pragma unroll
    for (int kh = 0; kh < 2; kh++) {
      f32x16 z;
#pragma unroll
      for (int r = 0; r < 16; r++) z[r] = 0.f;
      unsigned row = (unsigned)kh * 32u + l31;
#pragma unroll
      for (int kq = 0; kq < 4; kq++) {
        int4 kf = *(const int4*)(sm + row * 128u +
                                 ((((unsigned)kq * 2u + hl) ^ (row & 7u)) << 4));
        z = __builtin_amdgcn_mfma_f32_32x32x16_bf16(
            __builtin_bit_cast(bf16x8, kf), qf[kq], z, 0, 0, 0);
      }
      st[kh] = z;
    }
    // online softmax; per-q stats need only lane <-> lane^32 exchange
    float vm = st[0][0];
#pragma unroll
    for (int kh = 0; kh < 2; kh++)
#pragma unroll
      for (int r = 0; r < 16; r++) vm = fmaxf(vm, st[kh][r]);
    vm = fmaxf(vm, __shfl_xor(vm, 32));
    float mnew = fmaxf(mh, vm);
    float alpha = exp2f(mh - mnew);
    mh = mnew;
    float ps = 0.f;
#pragma unroll
    for (int kh = 0; kh < 2; kh++)
#pragma unroll
      for (int r = 0; r < 16; r++) {
        float p = exp2f(st[kh][r] - mnew);
        st[kh][r] = p;
        ps += p;
      }
    lsum = lsum * alpha + ps;
#pragma unroll
    for (int dh = 0; dh < 2; dh++) accO[dh] = accO[dh] * alpha;
    // P -> wave-private LDS as [q][key] bf16 (reg-quad c = 4 consecutive keys)
#pragma unroll
    for (int kh = 0; kh < 2; kh++)
#pragma unroll
      for (int c = 0; c < 4; c++) {
        unsigned g = ((unsigned)c + 4u * (unsigned)kh) ^ (l31 & 7u);
        int2 pv = make_int2(pk_bf16(st[kh][c * 4 + 0], st[kh][c * 4 + 1]),
                            pk_bf16(st[kh][c * 4 + 2], st[kh][c * 4 + 3]));
        *(int2*)(sm + Pb + l31 * 128u + (g << 4) + hl * 8u) = pv;
      }
    // O^T += V^T * P^T (A = Vt frag, B = P frag); no barrier (wave-private P)
#pragma unroll
    for (int kqp = 0; kqp < 4; kqp++) {
      int4 pv = *(const int4*)(sm + Pb + l31 * 128u +
                               ((((unsigned)kqp * 2u + hl) ^ (l31 & 7u)) << 4));
      bf16x8 pf = __builtin_bit_cast(bf16x8, pv);
#pragma unroll
      for (int dh = 0; dh < 2; dh++) {
        unsigned row = (unsigned)dh * 32u + l31;
        int4 vf = *(const int4*)(sm + 8192u + row * 128u +
                                 ((((unsigned)kqp * 2u + hl) ^ (row & 7u)) << 4));
        accO[dh] = __builtin_amdgcn_mfma_f32_32x32x16_bf16(
            __builtin_bit_cast(bf16x8, vf), pf, accO[dh], 0, 0, 0);
      }
    }
  }
  // epilogue: write (m, l) and unnormalized O-partials (fp32)
  float lt = lsum + __shfl_xor(lsum, 32);
  unsigned gq = b * 4096u + qw + l31;
  if (hl == 0u) ml[ks * 16384u + gq] = make_float2(mh, lt);
#pragma unroll
  for (int dh = 0; dh < 2; dh++)
#pragma unroll
    for (int c = 0; c < 4; c++) {
      unsigned d0 = (unsigned)c * 8u + hl * 4u + (unsigned)dh * 32u;
      float4 ov = make_float4(accO[dh][c * 4 + 0], accO[dh][c * 4 + 1],
                              accO[dh][c * 4 + 2], accO[dh][c * 4 + 3]);
      *(float4*)(op + ks * 1048576u + gq * 64u + d0) = ov;
    }
}

// ---------------- kernel 3: combine K-split partials -----------------------
__global__ __launch_bounds__(256) void combine(const float* __restrict__ op,
                                               const float2* __restrict__ ml,
                                               float* __restrict__ out) {
  unsigned i = blockIdx.x * 256u + threadIdx.x;  // 262144 threads, 16B each
  unsigned q = i >> 4, c = i & 15u;
  float2 m0 = ml[q], m1 = ml[16384u + q], m2 = ml[32768u + q], m3 = ml[49152u + q];
  float M = fmaxf(fmaxf(m0.x, m1.x), fmaxf(m2.x, m3.x));
  float s0 = exp2f(m0.x - M), s1 = exp2f(m1.x - M), s2 = exp2f(m2.x - M),
        s3 = exp2f(m3.x - M);
  float L = m0.y * s0 + m1.y * s1 + m2.y * s2 + m3.y * s3;
  float4 o0 = *(const float4*)(op + q * 64u + c * 4u);
  float4 o1 = *(const float4*)(op + 1048576u + q * 64u + c * 4u);
  float4 o2 = *(const float4*)(op + 2097152u + q * 64u + c * 4u);
  float4 o3 = *(const float4*)(op + 3145728u + q * 64u + c * 4u);
  float inv = 1.0f / L;
  float4 r;
  r.x = (o0.x * s0 + o1.x * s1 + o2.x * s2 + o3.x * s3) * inv;
  r.y = (o0.y * s0 + o1.y * s1 + o2.y * s2 + o3.y * s3) * inv;
  r.z = (o0.z * s0 + o1.z * s1 + o2.z * s2 + o3.z * s3) * inv;
  r.w = (o0.w * s0 + o1.w * s1 + o2.w * s2 + o3.w * s3) * inv;
  *(float4*)(out + q * 64u + c * 4u) = r;
}

extern "C" void kernel_launch(void* const* d_in, const int* in_sizes, int n_in,
                              void* d_out, int out_size, void* d_ws,
                              size_t ws_size, hipStream_t stream) {
  const float* x = (const float*)d_in[0];
  const float* Wq = (const float*)d_in[1];
  const float* bq = (const float*)d_in[2];
  const float* Wk = (const float*)d_in[3];
  const float* bk = (const float*)d_in[4];
  const float* Wv = (const float*)d_in[5];
  const float* bv = (const float*)d_in[6];
  char* ws = (char*)d_ws;
  unsigned short* wt = (unsigned short*)(ws + WT_OFF);
  unsigned short* qb = (unsigned short*)(ws + Q_OFF);
  unsigned short* kb = (unsigned short*)(ws + K_OFF);
  unsigned short* vtb = (unsigned short*)(ws + VT_OFF);
  float2* mlp = (float2*)(ws + ML_OFF);
  float* opp = (float*)(ws + OP_OFF);
  float* outp = (float*)d_out;

  prep_w<<<384, 256, 0, stream>>>(Wq, Wk, Wv, wt);
  qkv_proj<<<512, 256, 0, stream>>>(x, wt, bq, bk, bv, qb, kb, vtb);
  attn<<<512, 256, 0, stream>>>(qb, kb, vtb, mlp, opp);
  combine<<<1024, 256, 0, stream>>>(opp, mlp, outp);
}